// Round 3
// baseline (477.197 us; speedup 1.0000x reference)
//
#include <hip/hip_runtime.h>

// ---------------------------------------------------------------------------
// LRU single step, fused.
//   state = Lambda * x0 + Bn @ u          (complex; stored PLANAR re|im)
//   y     = C1 @ x0_re + C2 @ x0_im + (E+D) @ u     (real, via reformulation)
// where C1 = C_re*lam_re - C_im*lam_im (per state column h),
//       C2 = -(C_re*lam_im + C_im*lam_re),
//       E  = C_re @ Bn_re - C_im @ Bn_im  (256x256, precomputed),
//       Bn = B * exp(gamma_log)[:,None].
// Scratch lives in __device__ globals. All state writes bounds-guarded by
// the harness-reported out_size, so either planar-re-only or planar-re+im
// conventions are handled safely.
// ---------------------------------------------------------------------------

typedef __attribute__((ext_vector_type(8))) short bf16x8;
typedef __attribute__((ext_vector_type(4))) float f32x4;
typedef unsigned short u16;

#define N_ROWS 32768
#define IN_DIM 256
#define SD 512
#define OUT_DIM 256
#define ROWS 32          // rows per block in main kernel

// scratch in static device memory
__device__ float g_lam[3 * SD];                 // lam_re | lam_im | g
__device__ u16   g_W1[2 * SD * IN_DIM];         // [1024][256] bf16, PLANAR: rows [0,512)=Bn_re, [512,1024)=Bn_im
__device__ u16   g_Wy[OUT_DIM * 1280];          // [256][1280] bf16

__device__ __forceinline__ u16 f2b(float f) {
    union { float f; unsigned int u; } v; v.f = f;
    unsigned int r = v.u + 0x7FFFu + ((v.u >> 16) & 1u);   // RNE
    return (u16)(r >> 16);
}

// --- prep 1: lam_re[512], lam_im[512], g[512] -------------------------------
__global__ void prep_lam(const float* __restrict__ nu_log,
                         const float* __restrict__ theta_log,
                         const float* __restrict__ gamma_log) {
    int t = threadIdx.x;
    if (t < SD) {
        float mod = expf(-expf(nu_log[t]));
        float th  = expf(theta_log[t]);
        g_lam[t]        = mod * cosf(th);
        g_lam[SD + t]   = mod * sinf(th);
        g_lam[2*SD + t] = expf(gamma_log[t]);
    }
}

// --- prep 2: W1 bf16 [1024][256] planar: row h = Bn_re[h], row 512+h = Bn_im[h]
__global__ void prep_W1(const float* __restrict__ B_re, const float* __restrict__ B_im) {
    int idx = blockIdx.x * 256 + threadIdx.x;      // 1024*256 elements
    int r = idx >> 8, k = idx & 255;
    int h = r & 511;
    float g = g_lam[2*SD + h];
    const float* src = (r < 512) ? B_re : B_im;
    g_W1[idx] = f2b(src[h*IN_DIM + k] * g);
}

// --- prep 3: Wy cols [0,512)=C1, [512,1024)=C2 ------------------------------
__global__ void prep_WyC(const float* __restrict__ C_re, const float* __restrict__ C_im) {
    int idx = blockIdx.x * 256 + threadIdx.x;      // 256*1024 elements
    int o = idx >> 10, c = idx & 1023;
    int h = c & 511;
    float cr = C_re[o*SD + h], ci = C_im[o*SD + h];
    float lre = g_lam[h], lim = g_lam[SD + h];
    float v = (c < 512) ? (cr*lre - ci*lim) : (-(cr*lim + ci*lre));
    g_Wy[(size_t)o*1280 + c] = f2b(v);
}

// --- prep 4: Wy cols [1024,1280) = E + D  (no LDS; caches suffice) ---------
__global__ void prep_WyE(const float* __restrict__ B_re, const float* __restrict__ B_im,
                         const float* __restrict__ C_re, const float* __restrict__ C_im,
                         const float* __restrict__ D) {
    int idx = blockIdx.x * 256 + threadIdx.x;      // 256*256 threads total
    int o = idx >> 8, j = idx & 255;
    float acc = 0.f;
    #pragma unroll 4
    for (int h = 0; h < SD; ++h) {
        float g = g_lam[2*SD + h];
        acc += (C_re[o*SD + h] * B_re[h*IN_DIM + j]
              - C_im[o*SD + h] * B_im[h*IN_DIM + j]) * g;
    }
    g_Wy[(size_t)o*1280 + 1024 + j] = f2b(acc + D[o*IN_DIM + j]);
}

// --- main fused kernel ------------------------------------------------------
// grid = 1024 blocks, 256 threads (4 waves). Per block: 32 rows.
// Phase A: state = lam*x0 + u @ W1^T, W1 planar -> cols [0,512)=Bu_re, [512,1024)=Bu_im
// Phase B: y = [x0_re | x0_im | u] @ Wy^T
__global__ __launch_bounds__(256) void lru_main(
    const float* __restrict__ u, const float* __restrict__ x0_re,
    const float* __restrict__ x0_im,
    float* __restrict__ y_out, float* __restrict__ st_out,
    long long st_limit)     // floats available in the state region of d_out
{
    __shared__ u16 Xu[ROWS * 264];    // u tile bf16, pad 256->264 (16B-aligned rows)
    __shared__ u16 Xs[ROWS * 520];    // x0 chunk bf16, pad 512->520
    __shared__ float lamL[1024];

    const int tid  = threadIdx.x;
    const int wv   = tid >> 6;
    const int lane = tid & 63;
    const int quad = lane >> 4;
    const int l16  = lane & 15;
    const int kq   = quad * 8;
    const size_t n0 = (size_t)blockIdx.x * ROWS;

    for (int i = tid; i < 1024; i += 256) lamL[i] = g_lam[i];

    // stage u tile -> bf16 LDS
    for (int i = tid; i < ROWS * 64; i += 256) {
        int r = i >> 6, c4 = i & 63;
        float4 v = ((const float4*)(u + (n0 + r) * IN_DIM))[c4];
        ushort4 b;
        b.x = f2b(v.x); b.y = f2b(v.y); b.z = f2b(v.z); b.w = f2b(v.w);
        *(ushort4*)(&Xu[r * 264 + c4 * 4]) = b;
    }
    __syncthreads();

    // ---------------- Phase A: state --------------------------------------
    for (int s = 0; s < 4; ++s) {
        const int colbase = s * 256 + wv * 64;
        const bool is_im = (colbase >= 512);          // wave-uniform
        f32x4 acc[2][4];
        #pragma unroll
        for (int mt = 0; mt < 2; ++mt)
            #pragma unroll
            for (int ct = 0; ct < 4; ++ct)
                acc[mt][ct] = f32x4{0.f, 0.f, 0.f, 0.f};

        for (int k0 = 0; k0 < IN_DIM; k0 += 32) {
            bf16x8 a[2], b[4];
            a[0] = *(const bf16x8*)(&Xu[l16 * 264 + k0 + kq]);
            a[1] = *(const bf16x8*)(&Xu[(16 + l16) * 264 + k0 + kq]);
            #pragma unroll
            for (int ct = 0; ct < 4; ++ct)
                b[ct] = *(const bf16x8*)(g_W1 + (size_t)(colbase + ct*16 + l16) * IN_DIM + k0 + kq);
            #pragma unroll
            for (int mt = 0; mt < 2; ++mt)
                #pragma unroll
                for (int ct = 0; ct < 4; ++ct)
                    acc[mt][ct] = __builtin_amdgcn_mfma_f32_16x16x32_bf16(
                        a[mt], b[ct], acc[mt][ct], 0, 0, 0);
        }
        // epilogue: v = lam*x0 + Bu, store PLANAR (re block, then im block)
        #pragma unroll
        for (int mt = 0; mt < 2; ++mt) {
            #pragma unroll
            for (int ct = 0; ct < 4; ++ct) {
                const int col = colbase + ct * 16 + l16;
                const int h = col & 511;
                const float lre = lamL[h], lim = lamL[512 + h];
                #pragma unroll
                for (int r = 0; r < 4; ++r) {
                    const size_t n = n0 + mt * 16 + quad * 4 + r;
                    const float xr = x0_re[n * SD + h];
                    const float xi = x0_im[n * SD + h];
                    float v = acc[mt][ct][r];
                    v += is_im ? (lre * xi + lim * xr) : (lre * xr - lim * xi);
                    const long long idx = (is_im ? (long long)N_ROWS * SD : 0)
                                        + (long long)n * SD + h;
                    if (idx < st_limit) st_out[idx] = v;
                }
            }
        }
    }

    // ---------------- Phase B: y ------------------------------------------
    f32x4 accy[2][4];
    #pragma unroll
    for (int mt = 0; mt < 2; ++mt)
        #pragma unroll
        for (int ct = 0; ct < 4; ++ct)
            accy[mt][ct] = f32x4{0.f, 0.f, 0.f, 0.f};

    for (int chunk = 0; chunk < 2; ++chunk) {
        const float* __restrict__ src = chunk ? x0_im : x0_re;
        __syncthreads();                      // protect Xs from previous chunk readers
        for (int i = tid; i < ROWS * 128; i += 256) {
            int r = i >> 7, c4 = i & 127;
            float4 v = ((const float4*)(src + (n0 + r) * SD))[c4];
            ushort4 b;
            b.x = f2b(v.x); b.y = f2b(v.y); b.z = f2b(v.z); b.w = f2b(v.w);
            *(ushort4*)(&Xs[r * 520 + c4 * 4]) = b;
        }
        __syncthreads();
        const int kbase = chunk * 512;
        for (int k0 = 0; k0 < SD; k0 += 32) {
            bf16x8 a[2], b[4];
            a[0] = *(const bf16x8*)(&Xs[l16 * 520 + k0 + kq]);
            a[1] = *(const bf16x8*)(&Xs[(16 + l16) * 520 + k0 + kq]);
            #pragma unroll
            for (int ct = 0; ct < 4; ++ct)
                b[ct] = *(const bf16x8*)(g_Wy + (size_t)(wv*64 + ct*16 + l16) * 1280 + kbase + k0 + kq);
            #pragma unroll
            for (int mt = 0; mt < 2; ++mt)
                #pragma unroll
                for (int ct = 0; ct < 4; ++ct)
                    accy[mt][ct] = __builtin_amdgcn_mfma_f32_16x16x32_bf16(
                        a[mt], b[ct], accy[mt][ct], 0, 0, 0);
        }
    }
    // u chunk (Xu still valid)
    for (int k0 = 0; k0 < IN_DIM; k0 += 32) {
        bf16x8 a[2], b[4];
        a[0] = *(const bf16x8*)(&Xu[l16 * 264 + k0 + kq]);
        a[1] = *(const bf16x8*)(&Xu[(16 + l16) * 264 + k0 + kq]);
        #pragma unroll
        for (int ct = 0; ct < 4; ++ct)
            b[ct] = *(const bf16x8*)(g_Wy + (size_t)(wv*64 + ct*16 + l16) * 1280 + 1024 + k0 + kq);
        #pragma unroll
        for (int mt = 0; mt < 2; ++mt)
            #pragma unroll
            for (int ct = 0; ct < 4; ++ct)
                accy[mt][ct] = __builtin_amdgcn_mfma_f32_16x16x32_bf16(
                    a[mt], b[ct], accy[mt][ct], 0, 0, 0);
    }
    // y epilogue
    #pragma unroll
    for (int mt = 0; mt < 2; ++mt) {
        #pragma unroll
        for (int ct = 0; ct < 4; ++ct) {
            const int col = wv * 64 + ct * 16 + l16;
            #pragma unroll
            for (int r = 0; r < 4; ++r) {
                const size_t n = n0 + mt * 16 + quad * 4 + r;
                y_out[n * OUT_DIM + col] = accy[mt][ct][r];
            }
        }
    }
}

extern "C" void kernel_launch(void* const* d_in, const int* in_sizes, int n_in,
                              void* d_out, int out_size, void* d_ws, size_t ws_size,
                              hipStream_t stream) {
    const float* u         = (const float*)d_in[0];
    const float* x0_re     = (const float*)d_in[1];
    const float* x0_im     = (const float*)d_in[2];
    const float* nu_log    = (const float*)d_in[3];
    const float* theta_log = (const float*)d_in[4];
    const float* gamma_log = (const float*)d_in[5];
    const float* B_re      = (const float*)d_in[6];
    const float* B_im      = (const float*)d_in[7];
    const float* C_re      = (const float*)d_in[8];
    const float* C_im      = (const float*)d_in[9];
    const float* D         = (const float*)d_in[10];

    float* y_out  = (float*)d_out;
    float* st_out = y_out + (size_t)N_ROWS * OUT_DIM;
    long long st_limit = (long long)out_size - (long long)N_ROWS * OUT_DIM;

    prep_lam<<<1, 512, 0, stream>>>(nu_log, theta_log, gamma_log);
    prep_W1<<<1024, 256, 0, stream>>>(B_re, B_im);
    prep_WyC<<<1024, 256, 0, stream>>>(C_re, C_im);
    prep_WyE<<<256, 256, 0, stream>>>(B_re, B_im, C_re, C_im, D);
    lru_main<<<N_ROWS / ROWS, 256, 0, stream>>>(u, x0_re, x0_im, y_out, st_out, st_limit);
}